// Round 2
// baseline (2153.188 us; speedup 1.0000x reference)
//
#include <hip/hip_runtime.h>

typedef unsigned short u16;
typedef __attribute__((ext_vector_type(8))) short short8;
typedef __attribute__((ext_vector_type(4))) float floatx4;

#define NN 50000
#define NE 1600000
#define BN_EPS 1e-5f

__device__ __forceinline__ float bfu(u16 u) {
    union { unsigned u32; float f; } v; v.u32 = ((unsigned)u) << 16; return v.f;
}
__device__ __forceinline__ u16 f2bf(float f) {
    union { float f; unsigned u; } v; v.f = f;
    unsigned r = v.u + 0x7FFFu + ((v.u >> 16) & 1u);
    return (u16)(r >> 16);
}
// mode m: 1 = buffers hold float32, 0 = buffers hold bf16
__device__ __forceinline__ float ldf(const void* p, int i, int m) {
    return m ? ((const float*)p)[i] : bfu(((const u16*)p)[i]);
}

// K0: dtype detection. Read head of x as bf16; f32 data reinterpreted as bf16
// yields random-exponent garbage on even indices -> max explodes.
__global__ __launch_bounds__(256) void k_detect(const u16* __restrict__ x, int* __restrict__ mode) {
    float mx = 0.f;
    for (int i = threadIdx.x; i < 4096; i += 256) mx = fmaxf(mx, fabsf(bfu(x[i])));
#pragma unroll
    for (int o = 32; o > 0; o >>= 1) mx = fmaxf(mx, __shfl_down(mx, o));
    __shared__ float s[4];
    if ((threadIdx.x & 63) == 0) s[threadIdx.x >> 6] = mx;
    __syncthreads();
    if (threadIdx.x == 0) {
        float m2 = fmaxf(fmaxf(s[0], s[1]), fmaxf(s[2], s[3]));
        mode[0] = (m2 > 1e4f) ? 1 : 0;
    }
}

// K0b: canonicalize MFMA weights to bf16 ws copies (exact copy in bf16 mode).
__global__ __launch_bounds__(256) void k_cvtw(const void* __restrict__ Wfe0, const void* __restrict__ We1,
                                              u16* __restrict__ Wfe0c, u16* __restrict__ We1c,
                                              const int* __restrict__ mf) {
    int m = mf[0];
    int i = blockIdx.x * 256 + threadIdx.x;          // 96*256 = 24576 = 16384 + 8192
    if (i < 16384) Wfe0c[i] = m ? f2bf(((const float*)Wfe0)[i]) : ((const u16*)Wfe0)[i];
    else { int j = i - 16384; We1c[j] = m ? f2bf(((const float*)We1)[j]) : ((const u16*)We1)[j]; }
}

// K1: n1_l0[n][c] = relu(sum_i x[n][i] * Wn0[c][i])   [50000 x 64], stored bf16
__global__ __launch_bounds__(256) void k_enc0(const void* __restrict__ x, const void* __restrict__ Wn,
                                              u16* __restrict__ n1, const int* __restrict__ mf) {
    int m = mf[0];
    int tid = blockIdx.x * 256 + threadIdx.x;        // exactly 3.2M
    int n = tid >> 6, c = tid & 63;
    float acc = 0.f;
#pragma unroll
    for (int i = 0; i < 16; i++) acc += ldf(x, n * 16 + i, m) * ldf(Wn, c * 16 + i, m);
    n1[tid] = f2bf(fmaxf(acc, 0.f));
}

// K2: per-node positive / negative edge_attr sums (rank-1 segment-sum trick)
__global__ __launch_bounds__(256) void k_esum(const void* __restrict__ ea, const int* __restrict__ ei,
                                              float* __restrict__ sp, float* __restrict__ sn,
                                              const int* __restrict__ mf) {
    int m = mf[0];
    int e = blockIdx.x * 256 + threadIdx.x;          // exactly 1.6M
    float a = ldf(ea, e, m);
    int d = ei[NE + e];
    if (a > 0.f) atomicAdd(sp + d, a);
    else if (a < 0.f) atomicAdd(sn + d, a);
}

// K_PN: P[j] = sum_k relu(We0[k]) * Wfe0[j][64+k] ; N[j] = sum_k min(We0[k],0) * Wfe0[j][64+k]
__global__ void k_pn(const void* __restrict__ We0, const void* __restrict__ Wfe0,
                     float* __restrict__ PN, const int* __restrict__ mf) {
    int m = mf[0];
    int j = threadIdx.x;  // 128
    float p = 0.f, n = 0.f;
    for (int k = 0; k < 64; k++) {
        float w = ldf(We0, k, m);
        float wf = ldf(Wfe0, j * 128 + 64 + k, m);
        p += fmaxf(w, 0.f) * wf;
        n += fminf(w, 0.f) * wf;
    }
    PN[j] = p; PN[128 + j] = n;
}

// K34: fused node MLP l0 + BN + node encoder l1 -> n1_l1 [50000 x 64] bf16
__global__ __launch_bounds__(128) void k_node_l0(
    const u16* __restrict__ n1l0, const float* __restrict__ sp, const float* __restrict__ sn,
    const void* __restrict__ We0, const void* __restrict__ Wfn0, const void* __restrict__ bfn0,
    const void* __restrict__ g0, const void* __restrict__ b0,
    const void* __restrict__ rm0, const void* __restrict__ rv0,
    const void* __restrict__ Wn1, u16* __restrict__ n1l1, const int* __restrict__ mf) {
    int m = mf[0];
    __shared__ float f[4][128];
    __shared__ float xr[4][128];
    int t = threadIdx.x;
    int n0 = blockIdx.x * 4;
    {   // build f = concat(agg_l0, n1_l0) analytically
        int k = t;
        float w0 = (k < 64) ? ldf(We0, k, m) : 0.f;
        float wp = fmaxf(w0, 0.f), wn = fminf(w0, 0.f);
#pragma unroll
        for (int nb = 0; nb < 4; nb++) {
            int n = n0 + nb;
            f[nb][k] = (k < 64) ? (wp * sp[n] + wn * sn[n]) : bfu(n1l0[n * 64 + (k - 64)]);
        }
    }
    __syncthreads();
    {   // x_l1 = BN(relu(f @ Wfn0^T + bfn0))
        int j = t;
        float a0 = 0.f, a1 = 0.f, a2 = 0.f, a3 = 0.f;
        for (int k = 0; k < 128; k++) {
            float w = ldf(Wfn0, j * 128 + k, m);
            a0 += w * f[0][k]; a1 += w * f[1][k]; a2 += w * f[2][k]; a3 += w * f[3][k];
        }
        float bias = ldf(bfn0, j, m);
        float sc = ldf(g0, j, m) * rsqrtf(ldf(rv0, j, m) + BN_EPS);
        float sh = ldf(b0, j, m) - ldf(rm0, j, m) * sc;
        xr[0][j] = fmaxf(a0 + bias, 0.f) * sc + sh;
        xr[1][j] = fmaxf(a1 + bias, 0.f) * sc + sh;
        xr[2][j] = fmaxf(a2 + bias, 0.f) * sc + sh;
        xr[3][j] = fmaxf(a3 + bias, 0.f) * sc + sh;
    }
    __syncthreads();
    {   // n1_l1 = relu(x_l1 @ Wn1^T)
        int c = t & 63;
        int g = t >> 6;  // 0,1
        for (int nb = g; nb < 4; nb += 2) {
            float acc = 0.f;
            for (int k = 0; k < 128; k++) acc += ldf(Wn1, c * 128 + k, m) * xr[nb][k];
            n1l1[(n0 + nb) * 64 + c] = f2bf(fmaxf(acc, 0.f));
        }
    }
}

// K5: fused edge pipeline (layer0 edge MLP + layer1 edge encoder + scatter-add), MFMA.
__global__ __launch_bounds__(256) void k_edge(
    const void* __restrict__ ea, const int* __restrict__ ei,
    const u16* __restrict__ n1l0,
    const u16* __restrict__ Wfe0c, const void* __restrict__ bfe0,
    const float* __restrict__ PN,
    const u16* __restrict__ We1c,
    float* __restrict__ agg, const int* __restrict__ mf) {
    int m = mf[0];
    __shared__ __align__(16) u16 h0s[16][72];   // stride 144B: 16B aligned
    __shared__ __align__(16) u16 h1s[16][136];  // stride 272B: 16B aligned
    __shared__ float aes[16];
    __shared__ int dsts[16];
    __shared__ int srcs[16];
    int t = threadIdx.x;
    int e0 = blockIdx.x * 16;
    if (t < 16) {
        int eg = e0 + t;
        aes[t] = ldf(ea, eg, m);
        srcs[t] = ei[eg];
        dsts[t] = ei[NE + eg];
    }
    __syncthreads();
#pragma unroll
    for (int i = 0; i < 4; i++) {
        int idx = t + i * 256;
        int e = idx >> 6, c = idx & 63;
        float v = bfu(n1l0[srcs[e] * 64 + c]) + bfu(n1l0[dsts[e] * 64 + c]);
        h0s[e][c] = f2bf(v);
    }
    __syncthreads();
    int lane = t & 63;
    int w = t >> 6;       // wave 0..3
    int q = lane >> 4;    // quad
    int nidx = lane & 15;
    // GEMM1: D1[e][j] = sum_{k<64} h0s[e][k] * Wfe0[j][k]
    short8 a0 = *(const short8*)&h0s[nidx][q * 8];
    short8 a1 = *(const short8*)&h0s[nidx][32 + q * 8];
#pragma unroll
    for (int jj = 0; jj < 2; jj++) {
        int jt = 2 * w + jj;
        int j = jt * 16 + nidx;
        const u16* wrow = Wfe0c + j * 128;
        short8 b0 = *(const short8*)&wrow[q * 8];
        short8 b1 = *(const short8*)&wrow[32 + q * 8];
        floatx4 acc = {0.f, 0.f, 0.f, 0.f};
        acc = __builtin_amdgcn_mfma_f32_16x16x32_bf16(a0, b0, acc, 0, 0, 0);
        acc = __builtin_amdgcn_mfma_f32_16x16x32_bf16(a1, b1, acc, 0, 0, 0);
        float bias = ldf(bfe0, j, m);
        float Pj = PN[j], Nj = PN[128 + j];
#pragma unroll
        for (int r = 0; r < 4; r++) {
            int e = q * 4 + r;                    // D: row=(lane>>4)*4+reg, col=lane&15
            float a = aes[e];
            float v = acc[r] + bias + a * (a > 0.f ? Pj : Nj);
            h1s[e][j] = f2bf(fmaxf(v, 0.f));
        }
    }
    __syncthreads();
    // GEMM2: e1'[e][c] = relu(sum_k h1[e][k] * We1[c][k]); agg[dst] += e1'
    {
        int c = w * 16 + nidx;
        const u16* wrow = We1c + c * 128;
        floatx4 acc = {0.f, 0.f, 0.f, 0.f};
#pragma unroll
        for (int ks = 0; ks < 4; ks++) {
            short8 aa = *(const short8*)&h1s[nidx][ks * 32 + q * 8];
            short8 bb = *(const short8*)&wrow[ks * 32 + q * 8];
            acc = __builtin_amdgcn_mfma_f32_16x16x32_bf16(aa, bb, acc, 0, 0, 0);
        }
#pragma unroll
        for (int r = 0; r < 4; r++) {
            int e = q * 4 + r;
            float v = fmaxf(acc[r], 0.f);
            atomicAdd(agg + dsts[e] * 64 + c, v);
        }
    }
}

// K6: node MLP l1 + BN -> d_out (dtype per mode)
__global__ __launch_bounds__(128) void k_node_l1(
    const u16* __restrict__ n1l1, const float* __restrict__ agg,
    const void* __restrict__ Wfn1, const void* __restrict__ bfn1,
    const void* __restrict__ g1, const void* __restrict__ b1,
    const void* __restrict__ rm1, const void* __restrict__ rv1,
    void* __restrict__ out, const int* __restrict__ mf) {
    int m = mf[0];
    __shared__ float f[4][128];
    int t = threadIdx.x, n0 = blockIdx.x * 4;
#pragma unroll
    for (int nb = 0; nb < 4; nb++) {
        int n = n0 + nb;
        f[nb][t] = (t < 64) ? agg[n * 64 + t] : bfu(n1l1[n * 64 + (t - 64)]);
    }
    __syncthreads();
    int j = t;
    float a0 = 0.f, a1 = 0.f, a2 = 0.f, a3 = 0.f;
    for (int k = 0; k < 128; k++) {
        float w = ldf(Wfn1, j * 128 + k, m);
        a0 += w * f[0][k]; a1 += w * f[1][k]; a2 += w * f[2][k]; a3 += w * f[3][k];
    }
    float bias = ldf(bfn1, j, m);
    float sc = ldf(g1, j, m) * rsqrtf(ldf(rv1, j, m) + BN_EPS);
    float sh = ldf(b1, j, m) - ldf(rm1, j, m) * sc;
    float o0 = fmaxf(a0 + bias, 0.f) * sc + sh;
    float o1 = fmaxf(a1 + bias, 0.f) * sc + sh;
    float o2 = fmaxf(a2 + bias, 0.f) * sc + sh;
    float o3 = fmaxf(a3 + bias, 0.f) * sc + sh;
    if (m) {
        float* o = (float*)out;
        o[(n0 + 0) * 128 + j] = o0; o[(n0 + 1) * 128 + j] = o1;
        o[(n0 + 2) * 128 + j] = o2; o[(n0 + 3) * 128 + j] = o3;
    } else {
        u16* o = (u16*)out;
        o[(n0 + 0) * 128 + j] = f2bf(o0); o[(n0 + 1) * 128 + j] = f2bf(o1);
        o[(n0 + 2) * 128 + j] = f2bf(o2); o[(n0 + 3) * 128 + j] = f2bf(o3);
    }
}

extern "C" void kernel_launch(void* const* d_in, const int* in_sizes, int n_in,
                              void* d_out, int out_size, void* d_ws, size_t ws_size,
                              hipStream_t stream) {
    const void* x    = d_in[0];
    const void* ea   = d_in[1];
    const int*  ei   = (const int*)d_in[2];
    const void* Wn0  = d_in[3];
    const void* We0  = d_in[4];
    const void* Wfn0 = d_in[5];
    const void* bfn0 = d_in[6];
    const void* Wfe0 = d_in[7];
    const void* bfe0 = d_in[8];
    const void* g0   = d_in[9];
    const void* b0   = d_in[10];
    const void* rm0  = d_in[11];
    const void* rv0  = d_in[12];
    const void* Wn1  = d_in[13];
    const void* We1  = d_in[14];
    const void* Wfn1 = d_in[15];
    const void* bfn1 = d_in[16];
    // d_in[17] (l1_Wfe), d_in[18] (l1_bfe): dead — layer-1 edge output is discarded
    const void* g1   = d_in[19];
    const void* b1   = d_in[20];
    const void* rm1  = d_in[21];
    const void* rv1  = d_in[22];

    float* wsf   = (float*)d_ws;
    float* agg   = wsf;                          // 3,200,000 f32
    u16*   n1l0  = (u16*)(wsf + 3200000);        // 3,200,000 u16 (1.6M f32 slots)
    u16*   n1l1  = (u16*)(wsf + 4800000);        // 3,200,000 u16
    float* sp    = wsf + 6400000;                // 50,000
    float* sn    = wsf + 6450000;                // 50,000
    float* PN    = wsf + 6500000;                // 256
    u16*   Wfe0c = (u16*)(wsf + 6500256);        // 16,384 u16 (8192 f32 slots)
    u16*   We1c  = (u16*)(wsf + 6508448);        // 8,192 u16 (4096 f32 slots)
    int*   mode  = (int*)(wsf + 6512544);        // 1

    hipMemsetAsync(sp, 0, 100000 * sizeof(float), stream);       // sp + sn
    hipMemsetAsync(agg, 0, 3200000 * sizeof(float), stream);

    k_detect<<<1, 256, 0, stream>>>((const u16*)x, mode);
    k_cvtw<<<96, 256, 0, stream>>>(Wfe0, We1, Wfe0c, We1c, mode);
    k_enc0<<<12500, 256, 0, stream>>>(x, Wn0, n1l0, mode);
    k_esum<<<6250, 256, 0, stream>>>(ea, ei, sp, sn, mode);
    k_pn<<<1, 128, 0, stream>>>(We0, Wfe0, PN, mode);
    k_node_l0<<<12500, 128, 0, stream>>>(n1l0, sp, sn, We0, Wfn0, bfn0,
                                         g0, b0, rm0, rv0, Wn1, n1l1, mode);
    k_edge<<<100000, 256, 0, stream>>>(ea, ei, n1l0, Wfe0c, bfe0, PN, We1c, agg, mode);
    k_node_l1<<<12500, 128, 0, stream>>>(n1l1, agg, Wfn1, bfn1,
                                         g1, b1, rm1, rv1, d_out, mode);
}

// Round 3
// 709.338 us; speedup vs baseline: 3.0355x; 3.0355x over previous
//
#include <hip/hip_runtime.h>

typedef unsigned short u16;
typedef __attribute__((ext_vector_type(8))) short short8;
typedef __attribute__((ext_vector_type(4))) float floatx4;

#define NN 50000
#define NE 1600000
#define BN_EPS 1e-5f

__device__ __forceinline__ float bfu(u16 u) {
    union { unsigned u32; float f; } v; v.u32 = ((unsigned)u) << 16; return v.f;
}
__device__ __forceinline__ u16 f2bf(float f) {
    union { float f; unsigned u; } v; v.f = f;
    unsigned r = v.u + 0x7FFFu + ((v.u >> 16) & 1u);
    return (u16)(r >> 16);
}
// mode m: 1 = buffers hold float32, 0 = buffers hold bf16
__device__ __forceinline__ float ldf(const void* p, int i, int m) {
    return m ? ((const float*)p)[i] : bfu(((const u16*)p)[i]);
}

// K0: dtype detection (f32 reinterpreted as bf16 -> random-exponent garbage).
__global__ __launch_bounds__(256) void k_detect(const u16* __restrict__ x, int* __restrict__ mode) {
    float mx = 0.f;
    for (int i = threadIdx.x; i < 4096; i += 256) mx = fmaxf(mx, fabsf(bfu(x[i])));
#pragma unroll
    for (int o = 32; o > 0; o >>= 1) mx = fmaxf(mx, __shfl_down(mx, o));
    __shared__ float s[4];
    if ((threadIdx.x & 63) == 0) s[threadIdx.x >> 6] = mx;
    __syncthreads();
    if (threadIdx.x == 0) {
        float m2 = fmaxf(fmaxf(s[0], s[1]), fmaxf(s[2], s[3]));
        mode[0] = (m2 > 1e4f) ? 1 : 0;
    }
}

// K0b: canonicalize all MFMA-consumed weights to bf16 ws copies.
// Layout in dst: Wfe0[16384] | We1[8192] | Wfn0[16384] | Wn1[8192] | Wfn1[16384]
__global__ __launch_bounds__(256) void k_cvtw(const void* __restrict__ W0, const void* __restrict__ W1,
                                              const void* __restrict__ W2, const void* __restrict__ W3,
                                              const void* __restrict__ W4,
                                              u16* __restrict__ dst, const int* __restrict__ mf) {
    int m = mf[0];
    int i = blockIdx.x * 256 + threadIdx.x;   // 65536 total
    const void* src; int off;
    if (i < 16384)      { src = W0; off = i; }
    else if (i < 24576) { src = W1; off = i - 16384; }
    else if (i < 40960) { src = W2; off = i - 24576; }
    else if (i < 49152) { src = W3; off = i - 40960; }
    else                { src = W4; off = i - 49152; }
    dst[i] = m ? f2bf(((const float*)src)[off]) : ((const u16*)src)[off];
}

// K1: n1_l0[n][c] = relu(sum_i x[n][i]*Wn0[c][i])  [50000 x 64] bf16. LDS-staged Wn0.
__global__ __launch_bounds__(256) void k_enc0(const void* __restrict__ x, const void* __restrict__ Wn,
                                              u16* __restrict__ n1, const int* __restrict__ mf) {
    int m = mf[0];
    __shared__ float Wns[64 * 17];
    __shared__ float xsh[4][16];
    int t = threadIdx.x;
    int n0 = blockIdx.x * 4;
    for (int i = t; i < 1024; i += 256) Wns[(i >> 4) * 17 + (i & 15)] = ldf(Wn, i, m);
    if (t < 64) xsh[t >> 4][t & 15] = ldf(x, n0 * 16 + t, m);
    __syncthreads();
    int n = t >> 6, c = t & 63;
    float acc = 0.f;
#pragma unroll
    for (int i = 0; i < 16; i++) acc += xsh[n][i] * Wns[c * 17 + i];
    n1[(n0 + n) * 64 + c] = f2bf(fmaxf(acc, 0.f));
}

// K2: per-node positive / negative edge_attr sums (rank-1 segment-sum trick)
__global__ __launch_bounds__(256) void k_esum(const void* __restrict__ ea, const int* __restrict__ ei,
                                              float* __restrict__ sp, float* __restrict__ sn,
                                              const int* __restrict__ mf) {
    int m = mf[0];
    int e = blockIdx.x * 256 + threadIdx.x;
    float a = ldf(ea, e, m);
    int d = ei[NE + e];
    if (a > 0.f) atomicAdd(sp + d, a);
    else if (a < 0.f) atomicAdd(sn + d, a);
}

// K_PN: P[j] = sum_k relu(We0[k])*Wfe0[j][64+k]; N[j] = sum_k min(We0[k],0)*Wfe0[j][64+k]
__global__ void k_pn(const void* __restrict__ We0, const void* __restrict__ Wfe0,
                     float* __restrict__ PN, const int* __restrict__ mf) {
    int m = mf[0];
    int j = threadIdx.x;  // 128
    float p = 0.f, n = 0.f;
    for (int k = 0; k < 64; k++) {
        float w = ldf(We0, k, m);
        float wf = ldf(Wfe0, j * 128 + 64 + k, m);
        p += fmaxf(w, 0.f) * wf;
        n += fminf(w, 0.f) * wf;
    }
    PN[j] = p; PN[128 + j] = n;
}

// K34: fused node MLP l0 + BN + node encoder l1 -> n1_l1 [50000 x 64] bf16. MFMA, 64 nodes/block.
__global__ __launch_bounds__(256) void k_node_l0(
    const u16* __restrict__ n1l0, const float* __restrict__ sp, const float* __restrict__ sn,
    const void* __restrict__ We0, const u16* __restrict__ Wfn0c, const void* __restrict__ bfn0,
    const void* __restrict__ g0, const void* __restrict__ b0,
    const void* __restrict__ rm0, const void* __restrict__ rv0,
    const u16* __restrict__ Wn1c, u16* __restrict__ n1l1, const int* __restrict__ mf) {
    int m = mf[0];
    __shared__ __align__(16) u16 fs[64][136];
    __shared__ __align__(16) u16 xs[64][136];
    int t = threadIdx.x;
    int n0 = blockIdx.x * 64;
    {   // fs[row][col] = concat(analytic agg_l0, n1_l0), bf16
        int col = t & 127;
        int rbase = t >> 7;              // 0 or 1
        float wp = 0.f, wn = 0.f;
        if (col < 64) { float w0 = ldf(We0, col, m); wp = fmaxf(w0, 0.f); wn = fminf(w0, 0.f); }
#pragma unroll
        for (int i = 0; i < 32; i++) {
            int row = rbase + 2 * i;
            int n = n0 + row;
            float v = 0.f;
            if (n < NN) v = (col < 64) ? (wp * sp[n] + wn * sn[n]) : bfu(n1l0[n * 64 + col - 64]);
            fs[row][col] = f2bf(v);
        }
    }
    __syncthreads();
    int lane = t & 63, w = t >> 6, q = lane >> 4, nidx = lane & 15;
    // GEMM1: x1 = BN(relu(fs @ Wfn0^T + bfn0)) -> xs  (wave w: nodes w*16..w*16+15)
    {
        const u16* ar = &fs[w * 16 + nidx][0];
        short8 a0 = *(const short8*)&ar[q * 8];
        short8 a1 = *(const short8*)&ar[32 + q * 8];
        short8 a2 = *(const short8*)&ar[64 + q * 8];
        short8 a3 = *(const short8*)&ar[96 + q * 8];
#pragma unroll
        for (int jt = 0; jt < 8; jt++) {
            int j = jt * 16 + nidx;
            const u16* wr = Wfn0c + j * 128;
            floatx4 acc = {0.f, 0.f, 0.f, 0.f};
            acc = __builtin_amdgcn_mfma_f32_16x16x32_bf16(a0, *(const short8*)&wr[q * 8], acc, 0, 0, 0);
            acc = __builtin_amdgcn_mfma_f32_16x16x32_bf16(a1, *(const short8*)&wr[32 + q * 8], acc, 0, 0, 0);
            acc = __builtin_amdgcn_mfma_f32_16x16x32_bf16(a2, *(const short8*)&wr[64 + q * 8], acc, 0, 0, 0);
            acc = __builtin_amdgcn_mfma_f32_16x16x32_bf16(a3, *(const short8*)&wr[96 + q * 8], acc, 0, 0, 0);
            float bias = ldf(bfn0, j, m);
            float sc = ldf(g0, j, m) * rsqrtf(ldf(rv0, j, m) + BN_EPS);
            float sh = ldf(b0, j, m) - ldf(rm0, j, m) * sc;
#pragma unroll
            for (int r = 0; r < 4; r++) {
                int row = w * 16 + q * 4 + r;    // D: row=(lane>>4)*4+reg, col=lane&15
                xs[row][j] = f2bf(fmaxf(acc[r] + bias, 0.f) * sc + sh);
            }
        }
    }
    __syncthreads();
    // GEMM2: n1_l1 = relu(xs @ Wn1^T)  [64 x 64]
    {
        const u16* ar = &xs[w * 16 + nidx][0];
        short8 a0 = *(const short8*)&ar[q * 8];
        short8 a1 = *(const short8*)&ar[32 + q * 8];
        short8 a2 = *(const short8*)&ar[64 + q * 8];
        short8 a3 = *(const short8*)&ar[96 + q * 8];
#pragma unroll
        for (int jt = 0; jt < 4; jt++) {
            int j = jt * 16 + nidx;
            const u16* wr = Wn1c + j * 128;
            floatx4 acc = {0.f, 0.f, 0.f, 0.f};
            acc = __builtin_amdgcn_mfma_f32_16x16x32_bf16(a0, *(const short8*)&wr[q * 8], acc, 0, 0, 0);
            acc = __builtin_amdgcn_mfma_f32_16x16x32_bf16(a1, *(const short8*)&wr[32 + q * 8], acc, 0, 0, 0);
            acc = __builtin_amdgcn_mfma_f32_16x16x32_bf16(a2, *(const short8*)&wr[64 + q * 8], acc, 0, 0, 0);
            acc = __builtin_amdgcn_mfma_f32_16x16x32_bf16(a3, *(const short8*)&wr[96 + q * 8], acc, 0, 0, 0);
#pragma unroll
            for (int r = 0; r < 4; r++) {
                int row = w * 16 + q * 4 + r;
                int n = n0 + row;
                if (n < NN) n1l1[n * 64 + j] = f2bf(fmaxf(acc[r], 0.f));
            }
        }
    }
}

// K5: fused edge pipeline (layer0 edge MLP + layer1 edge encoder + scatter-add), MFMA.
__global__ __launch_bounds__(256) void k_edge(
    const void* __restrict__ ea, const int* __restrict__ ei,
    const u16* __restrict__ n1l0,
    const u16* __restrict__ Wfe0c, const void* __restrict__ bfe0,
    const float* __restrict__ PN,
    const u16* __restrict__ We1c,
    float* __restrict__ agg, const int* __restrict__ mf) {
    int m = mf[0];
    __shared__ __align__(16) u16 h0s[16][72];
    __shared__ __align__(16) u16 h1s[16][136];
    __shared__ float aes[16];
    __shared__ int dsts[16];
    __shared__ int srcs[16];
    int t = threadIdx.x;
    int e0 = blockIdx.x * 16;
    if (t < 16) {
        int eg = e0 + t;
        aes[t] = ldf(ea, eg, m);
        srcs[t] = ei[eg];
        dsts[t] = ei[NE + eg];
    }
    __syncthreads();
#pragma unroll
    for (int i = 0; i < 4; i++) {
        int idx = t + i * 256;
        int e = idx >> 6, c = idx & 63;
        float v = bfu(n1l0[srcs[e] * 64 + c]) + bfu(n1l0[dsts[e] * 64 + c]);
        h0s[e][c] = f2bf(v);
    }
    __syncthreads();
    int lane = t & 63;
    int w = t >> 6;
    int q = lane >> 4;
    int nidx = lane & 15;
    short8 a0 = *(const short8*)&h0s[nidx][q * 8];
    short8 a1 = *(const short8*)&h0s[nidx][32 + q * 8];
#pragma unroll
    for (int jj = 0; jj < 2; jj++) {
        int jt = 2 * w + jj;
        int j = jt * 16 + nidx;
        const u16* wrow = Wfe0c + j * 128;
        short8 b0 = *(const short8*)&wrow[q * 8];
        short8 b1 = *(const short8*)&wrow[32 + q * 8];
        floatx4 acc = {0.f, 0.f, 0.f, 0.f};
        acc = __builtin_amdgcn_mfma_f32_16x16x32_bf16(a0, b0, acc, 0, 0, 0);
        acc = __builtin_amdgcn_mfma_f32_16x16x32_bf16(a1, b1, acc, 0, 0, 0);
        float bias = ldf(bfe0, j, m);
        float Pj = PN[j], Nj = PN[128 + j];
#pragma unroll
        for (int r = 0; r < 4; r++) {
            int e = q * 4 + r;
            float a = aes[e];
            float v = acc[r] + bias + a * (a > 0.f ? Pj : Nj);
            h1s[e][j] = f2bf(fmaxf(v, 0.f));
        }
    }
    __syncthreads();
    {
        int c = w * 16 + nidx;
        const u16* wrow = We1c + c * 128;
        floatx4 acc = {0.f, 0.f, 0.f, 0.f};
#pragma unroll
        for (int ks = 0; ks < 4; ks++) {
            short8 aa = *(const short8*)&h1s[nidx][ks * 32 + q * 8];
            short8 bb = *(const short8*)&wrow[ks * 32 + q * 8];
            acc = __builtin_amdgcn_mfma_f32_16x16x32_bf16(aa, bb, acc, 0, 0, 0);
        }
#pragma unroll
        for (int r = 0; r < 4; r++) {
            int e = q * 4 + r;
            float v = fmaxf(acc[r], 0.f);
            atomicAdd(agg + dsts[e] * 64 + c, v);
        }
    }
}

// K6: node MLP l1 + BN -> d_out. MFMA, 64 nodes/block.
__global__ __launch_bounds__(256) void k_node_l1(
    const u16* __restrict__ n1l1, const float* __restrict__ agg,
    const u16* __restrict__ Wfn1c, const void* __restrict__ bfn1,
    const void* __restrict__ g1, const void* __restrict__ b1,
    const void* __restrict__ rm1, const void* __restrict__ rv1,
    void* __restrict__ out, const int* __restrict__ mf) {
    int m = mf[0];
    __shared__ __align__(16) u16 fs[64][136];
    int t = threadIdx.x;
    int n0 = blockIdx.x * 64;
    {
        int col = t & 127;
        int rbase = t >> 7;
#pragma unroll
        for (int i = 0; i < 32; i++) {
            int row = rbase + 2 * i;
            int n = n0 + row;
            float v = 0.f;
            if (n < NN) v = (col < 64) ? agg[n * 64 + col] : bfu(n1l1[n * 64 + col - 64]);
            fs[row][col] = f2bf(v);
        }
    }
    __syncthreads();
    int lane = t & 63, w = t >> 6, q = lane >> 4, nidx = lane & 15;
    const u16* ar = &fs[w * 16 + nidx][0];
    short8 a0 = *(const short8*)&ar[q * 8];
    short8 a1 = *(const short8*)&ar[32 + q * 8];
    short8 a2 = *(const short8*)&ar[64 + q * 8];
    short8 a3 = *(const short8*)&ar[96 + q * 8];
#pragma unroll
    for (int jt = 0; jt < 8; jt++) {
        int j = jt * 16 + nidx;
        const u16* wr = Wfn1c + j * 128;
        floatx4 acc = {0.f, 0.f, 0.f, 0.f};
        acc = __builtin_amdgcn_mfma_f32_16x16x32_bf16(a0, *(const short8*)&wr[q * 8], acc, 0, 0, 0);
        acc = __builtin_amdgcn_mfma_f32_16x16x32_bf16(a1, *(const short8*)&wr[32 + q * 8], acc, 0, 0, 0);
        acc = __builtin_amdgcn_mfma_f32_16x16x32_bf16(a2, *(const short8*)&wr[64 + q * 8], acc, 0, 0, 0);
        acc = __builtin_amdgcn_mfma_f32_16x16x32_bf16(a3, *(const short8*)&wr[96 + q * 8], acc, 0, 0, 0);
        float bias = ldf(bfn1, j, m);
        float sc = ldf(g1, j, m) * rsqrtf(ldf(rv1, j, m) + BN_EPS);
        float sh = ldf(b1, j, m) - ldf(rm1, j, m) * sc;
#pragma unroll
        for (int r = 0; r < 4; r++) {
            int row = w * 16 + q * 4 + r;
            int n = n0 + row;
            if (n < NN) {
                float v = fmaxf(acc[r] + bias, 0.f) * sc + sh;
                if (m) ((float*)out)[n * 128 + j] = v;
                else   ((u16*)out)[n * 128 + j] = f2bf(v);
            }
        }
    }
}

extern "C" void kernel_launch(void* const* d_in, const int* in_sizes, int n_in,
                              void* d_out, int out_size, void* d_ws, size_t ws_size,
                              hipStream_t stream) {
    const void* x    = d_in[0];
    const void* ea   = d_in[1];
    const int*  ei   = (const int*)d_in[2];
    const void* Wn0  = d_in[3];
    const void* We0  = d_in[4];
    const void* Wfn0 = d_in[5];
    const void* bfn0 = d_in[6];
    const void* Wfe0 = d_in[7];
    const void* bfe0 = d_in[8];
    const void* g0   = d_in[9];
    const void* b0   = d_in[10];
    const void* rm0  = d_in[11];
    const void* rv0  = d_in[12];
    const void* Wn1  = d_in[13];
    const void* We1  = d_in[14];
    const void* Wfn1 = d_in[15];
    const void* bfn1 = d_in[16];
    // d_in[17]/d_in[18] (l1_Wfe/l1_bfe): dead — layer-1 edge output discarded
    const void* g1   = d_in[19];
    const void* b1   = d_in[20];
    const void* rm1  = d_in[21];
    const void* rv1  = d_in[22];

    float* wsf   = (float*)d_ws;
    float* agg   = wsf;                          // 3,200,000 f32
    u16*   n1l0  = (u16*)(wsf + 3200000);        // 3.2M u16
    u16*   n1l1  = (u16*)(wsf + 4800000);        // 3.2M u16
    float* sp    = wsf + 6400000;                // 50,000
    float* sn    = wsf + 6450000;                // 50,000
    float* PN    = wsf + 6500000;                // 256
    u16*   Wc    = (u16*)(wsf + 6500256);        // 65,536 u16 canonical weights
    int*   mode  = (int*)(wsf + 6533024);
    u16* Wfe0c = Wc;
    u16* We1c  = Wc + 16384;
    u16* Wfn0c = Wc + 24576;
    u16* Wn1c  = Wc + 40960;
    u16* Wfn1c = Wc + 49152;

    hipMemsetAsync(sp, 0, 100000 * sizeof(float), stream);       // sp + sn
    hipMemsetAsync(agg, 0, 3200000 * sizeof(float), stream);

    k_detect<<<1, 256, 0, stream>>>((const u16*)x, mode);
    k_cvtw<<<256, 256, 0, stream>>>(Wfe0, We1, Wfn0, Wn1, Wfn1, Wc, mode);
    k_enc0<<<12500, 256, 0, stream>>>(x, Wn0, n1l0, mode);
    k_esum<<<6250, 256, 0, stream>>>(ea, ei, sp, sn, mode);
    k_pn<<<1, 128, 0, stream>>>(We0, Wfe0, PN, mode);
    k_node_l0<<<782, 256, 0, stream>>>(n1l0, sp, sn, We0, Wfn0c, bfn0,
                                       g0, b0, rm0, rv0, Wn1c, n1l1, mode);
    k_edge<<<100000, 256, 0, stream>>>(ea, ei, n1l0, Wfe0c, bfe0, PN, We1c, agg, mode);
    k_node_l1<<<782, 256, 0, stream>>>(n1l1, agg, Wfn1c, bfn1,
                                       g1, b1, rm1, rv1, d_out, mode);
}